// Round 1
// baseline (603.209 us; speedup 1.0000x reference)
//
#include <hip/hip_runtime.h>

// TokenSelection: B=32, S=8192, D=512, BLOCK_SIZE=64, NB=128, NUM_SELECTED=16
// keys: [32][8192][512] f32 (d_in[0]); compression_scores: [32][128] f32 (d_in[1])
// out:  [32][16*64][512] f32
// ws:   top-16 block indices per batch, 32*16 ints

#define NB 128
#define NSEL 16
#define BS 64
#define DIM 512
#define NBATCH 32

// One 64-lane wave per batch: iterative selection of top-16 with
// jax.lax.top_k semantics (descending value, ties -> smaller index).
__global__ void topk_kernel(const float* __restrict__ scores,
                            int* __restrict__ top) {
    const int b = blockIdx.x;
    const int lane = threadIdx.x;  // 0..63
    float s0 = scores[b * NB + lane];
    float s1 = scores[b * NB + 64 + lane];
    int i0 = lane;
    int i1 = lane + 64;
    #pragma unroll
    for (int it = 0; it < NSEL; ++it) {
        float bv; int bi;
        if (s0 > s1 || (s0 == s1 && i0 < i1)) { bv = s0; bi = i0; }
        else                                  { bv = s1; bi = i1; }
        // 64-lane butterfly arg-max
        #pragma unroll
        for (int off = 32; off >= 1; off >>= 1) {
            float ov = __shfl_xor(bv, off);
            int   oi = __shfl_xor(bi, off);
            if (ov > bv || (ov == bv && oi < bi)) { bv = ov; bi = oi; }
        }
        if (lane == 0) top[b * NSEL + it] = bi;
        if (bi == i0) s0 = -INFINITY;
        if (bi == i1) s1 = -INFINITY;
    }
}

// Flat float4 gather: out[b][sel][row][col] = keys[b][top[b*16+sel]][row][col]
// i = ((b*16 + sel)*64 + row)*128 + col   (col in float4 units, 128/row)
__global__ void gather_kernel(const float4* __restrict__ keys,
                              const int* __restrict__ top,
                              float4* __restrict__ out) {
    const int i = blockIdx.x * blockDim.x + threadIdx.x;
    const int col    = i & 127;        // f4 column within row
    const int row_g  = i >> 7;         // global output row (B*1024)
    const int within = row_g & 63;     // row within block
    const int selrow = row_g >> 6;     // b*16 + sel  (wave-uniform)
    const int b      = selrow >> 4;
    const int blk    = top[selrow];    // wave-uniform -> scalar load
    const int src    = ((b * NB + blk) * BS + within) * 128 + col;
    out[i] = keys[src];
}

extern "C" void kernel_launch(void* const* d_in, const int* in_sizes, int n_in,
                              void* d_out, int out_size, void* d_ws, size_t ws_size,
                              hipStream_t stream) {
    const float* keys   = (const float*)d_in[0];
    const float* scores = (const float*)d_in[1];
    float* out = (float*)d_out;
    int*   top = (int*)d_ws;

    topk_kernel<<<NBATCH, 64, 0, stream>>>(scores, top);

    const int total_f4 = NBATCH * NSEL * BS * (DIM / 4);  // 4,194,304
    gather_kernel<<<total_f4 / 256, 256, 0, stream>>>(
        (const float4*)keys, top, (float4*)out);
}

// Round 5
// 602.402 us; speedup vs baseline: 1.0013x; 1.0013x over previous
//
#include <hip/hip_runtime.h>

// TokenSelection: B=32, S=8192, D=512, BLOCK_SIZE=64, NB=128, NUM_SELECTED=16
// keys: [32][8192][512] f32 (d_in[0]); compression_scores: [32][128] f32 (d_in[1])
// out:  [32][16*64][512] f32
//
// Single fused kernel: 4 workgroups per (batch, sel) output block (2048 wg
// total -> full occupancy for a streaming copy). Every wave redundantly
// computes the iterative top-k (jax.lax.top_k semantics: descending value,
// ties -> smaller index) from the 128 block scores -- ~100 VALU ops + 2
// L2-cached loads, negligible -- then the workgroup streams its quarter of
// the selected 64x512 key block (32 KiB contiguous) to the output.
// No workspace, one launch.

#define NB 128
#define NSEL 16
#define BS 64
#define DIM 512
#define NBATCH 32
#define F4_PER_BLK (BS * DIM / 4)   // 8192 float4 per key block
#define CHUNKS 4                    // workgroups per key block
#define F4_PER_CHUNK (F4_PER_BLK / CHUNKS)  // 2048 float4 per workgroup

__global__ __launch_bounds__(256) void
token_sel_fused(const float4* __restrict__ keys,
                const float* __restrict__ scores,
                float4* __restrict__ out) {
    const int selrow = blockIdx.x >> 2;   // b*16 + sel, 0..511
    const int chunk  = blockIdx.x & 3;
    const int b   = selrow >> 4;
    const int sel = selrow & 15;
    const int lane = threadIdx.x & 63;

    // --- per-wave redundant top-k: find the sel-th largest block score ---
    float s0 = scores[b * NB + lane];
    float s1 = scores[b * NB + 64 + lane];
    int i0 = lane;
    int i1 = lane + 64;
    int blk = 0;
    for (int it = 0; it <= sel; ++it) {
        float bv; int bi;
        if (s0 > s1 || (s0 == s1 && i0 < i1)) { bv = s0; bi = i0; }
        else                                  { bv = s1; bi = i1; }
        #pragma unroll
        for (int off = 32; off >= 1; off >>= 1) {
            float ov = __shfl_xor(bv, off);
            int   oi = __shfl_xor(bi, off);
            if (ov > bv || (ov == bv && oi < bi)) { bv = ov; bi = oi; }
        }
        blk = bi;
        if (bi == i0) s0 = -INFINITY;
        if (bi == i1) s1 = -INFINITY;
    }

    // --- stream this workgroup's quarter of the selected block (32 KiB) ---
    const size_t off4 = (size_t)chunk * F4_PER_CHUNK;
    const float4* __restrict__ src =
        keys + (size_t)(b * NB + blk) * F4_PER_BLK + off4;
    float4* __restrict__ dst =
        out + (size_t)selrow * F4_PER_BLK + off4;
    #pragma unroll
    for (int t = threadIdx.x; t < F4_PER_CHUNK; t += 256) {
        dst[t] = src[t];
    }
}

extern "C" void kernel_launch(void* const* d_in, const int* in_sizes, int n_in,
                              void* d_out, int out_size, void* d_ws, size_t ws_size,
                              hipStream_t stream) {
    const float* keys   = (const float*)d_in[0];
    const float* scores = (const float*)d_in[1];
    float* out = (float*)d_out;

    token_sel_fused<<<NBATCH * NSEL * CHUNKS, 256, 0, stream>>>(
        (const float4*)keys, scores, (float4*)out);
}